// Round 1
// baseline (2358.601 us; speedup 1.0000x reference)
//
#include <hip/hip_runtime.h>
#include <hip/hip_bf16.h>

// ---------------------------------------------------------------------------
// VGNet: conv1(3->8,3x3,s1)+relu -> conv2(8->5,5x5,s2)+relu -> flatten(245)
//        -> l1(245->128)+relu -> APPNP(K=2, alpha=0.8) -> BatchNorm ->
//        mean-pool by graph -> MLP(128->64->5)
// Outputs: pred [G,5] then node_x [N,128], concatenated in d_out (fp32).
// ---------------------------------------------------------------------------

#define ALPHA 0.8f
#define BN_EPS 1e-5f

// ---------------- CNN encoder: conv1 + conv2 fused, one node per block -----
__global__ __launch_bounds__(256) void conv_fused(
    const float* __restrict__ x,
    const float* __restrict__ c1w, const float* __restrict__ c1b,
    const float* __restrict__ c2w, const float* __restrict__ c2b,
    float* __restrict__ h2out, int N)
{
    __shared__ float xs[3 * 19 * 19];   // 1083
    __shared__ float h1[8 * 17 * 17];   // 2312
    __shared__ float w1[8 * 3 * 3 * 3]; // 216
    __shared__ float b1[8];
    __shared__ float w2[5 * 8 * 5 * 5]; // 1000
    __shared__ float b2[5];

    int n = blockIdx.x;
    int t = threadIdx.x;
    const float* xp = x + (size_t)n * 1083;
    for (int i = t; i < 1083; i += 256) xs[i] = xp[i];
    for (int i = t; i < 216; i += 256) w1[i] = c1w[i];
    if (t < 8) b1[t] = c1b[t];
    for (int i = t; i < 1000; i += 256) w2[i] = c2w[i];
    if (t < 5) b2[t] = c2b[t];
    __syncthreads();

    // conv1: out [8][17][17], 3x3, stride 1, relu
    for (int idx = t; idx < 8 * 17 * 17; idx += 256) {
        int o = idx / 289;
        int rem = idx % 289;
        int y = rem / 17;
        int xx = rem % 17;
        float acc = b1[o];
        const float* wp = w1 + o * 27;
        #pragma unroll
        for (int ci = 0; ci < 3; ++ci)
            #pragma unroll
            for (int ky = 0; ky < 3; ++ky) {
                const float* xr = xs + ci * 361 + (y + ky) * 19 + xx;
                const float* wr = wp + ci * 9 + ky * 3;
                acc += xr[0] * wr[0] + xr[1] * wr[1] + xr[2] * wr[2];
            }
        h1[idx] = fmaxf(acc, 0.f);
    }
    __syncthreads();

    // conv2: out [5][7][7], 5x5, stride 2, relu -> h2out [N,245]
    if (t < 245) {
        int o = t / 49;
        int rem = t % 49;
        int y = rem / 7;
        int xx = rem % 7;
        float acc = b2[o];
        const float* wp = w2 + o * 200;
        #pragma unroll
        for (int ci = 0; ci < 8; ++ci)
            #pragma unroll
            for (int ky = 0; ky < 5; ++ky) {
                const float* hr = h1 + ci * 289 + (2 * y + ky) * 17 + 2 * xx;
                const float* wr = wp + ci * 25 + ky * 5;
                acc += hr[0] * wr[0] + hr[1] * wr[1] + hr[2] * wr[2]
                     + hr[3] * wr[3] + hr[4] * wr[4];
            }
        h2out[(size_t)n * 245 + t] = fmaxf(acc, 0.f);
    }
}

// ---------------- l1: h0[N,128] = relu(h2[N,245] @ l1w.T + l1b) ------------
// Block: 256 threads, 64-node tile in LDS; thread (f=t&127, g=t>>7) computes
// 32 node outputs for feature f with register accumulators.
__global__ __launch_bounds__(256) void l1_kernel(
    const float* __restrict__ h2, const float* __restrict__ l1w,
    const float* __restrict__ l1b, float* __restrict__ h0, int N)
{
    __shared__ float hs[64 * 245]; // 62.7 KB
    int t = threadIdx.x;
    int n0 = blockIdx.x * 64;
    int count = min(64, N - n0);
    for (int i = t; i < count * 245; i += 256) hs[i] = h2[(size_t)n0 * 245 + i];
    __syncthreads();

    int f = t & 127;
    int g = t >> 7; // 0 or 1
    int nbase = g * 32;
    float acc[32];
    #pragma unroll
    for (int j = 0; j < 32; ++j) acc[j] = 0.f;
    const float* wrow = l1w + f * 245;
    for (int k = 0; k < 245; ++k) {
        float wk = wrow[k];
        #pragma unroll
        for (int j = 0; j < 32; ++j) acc[j] += wk * hs[(nbase + j) * 245 + k];
    }
    float bias = l1b[f];
    for (int j = 0; j < 32; ++j) {
        int n = n0 + nbase + j;
        if (n < N) h0[(size_t)n * 128 + f] = fmaxf(acc[j] + bias, 0.f);
    }
}

// ---------------- graph-normalization prep --------------------------------
__global__ void deg_kernel(const int* __restrict__ col, const float* __restrict__ w,
                           float* __restrict__ deg, int E)
{
    int e = blockIdx.x * 256 + threadIdx.x;
    if (e < E) atomicAdd(&deg[col[e]], w[e]);
}

__global__ void cnt_kernel(const int* __restrict__ col, int* __restrict__ cnt, int E)
{
    int e = blockIdx.x * 256 + threadIdx.x;
    if (e < E) atomicAdd(&cnt[col[e]], 1);
}

__global__ void dinv_kernel(const float* __restrict__ deg, float* __restrict__ dinv, int N)
{
    int n = blockIdx.x * 256 + threadIdx.x;
    if (n < N) {
        float d = deg[n];
        dinv[n] = d > 0.f ? rsqrtf(d) : 0.f;
    }
}

// single-block exclusive scan over cnt[N] -> off[N+1]; also copies to cursor
__global__ __launch_bounds__(1024) void scan_kernel(
    const int* __restrict__ cnt, int* __restrict__ off,
    int* __restrict__ cursor, int N)
{
    __shared__ int buf[1024];
    __shared__ int carry;
    if (threadIdx.x == 0) carry = 0;
    __syncthreads();
    for (int base = 0; base < N; base += 1024) {
        int i = base + threadIdx.x;
        int v = (i < N) ? cnt[i] : 0;
        buf[threadIdx.x] = v;
        __syncthreads();
        for (int ofs = 1; ofs < 1024; ofs <<= 1) {
            int tmp = (threadIdx.x >= ofs) ? buf[threadIdx.x - ofs] : 0;
            __syncthreads();
            buf[threadIdx.x] += tmp;
            __syncthreads();
        }
        int incl = buf[threadIdx.x];
        if (i < N) {
            int excl = carry + incl - v;
            off[i] = excl;
            cursor[i] = excl;
        }
        int total = buf[1023];
        __syncthreads();
        if (threadIdx.x == 0) carry += total;
        __syncthreads();
    }
    if (threadIdx.x == 0) off[N] = carry;
}

__global__ void scatter_edges(const int* __restrict__ row, const int* __restrict__ col,
                              const float* __restrict__ w, const float* __restrict__ dinv,
                              int* __restrict__ cursor, int* __restrict__ src,
                              float* __restrict__ val, int E)
{
    int e = blockIdx.x * 256 + threadIdx.x;
    if (e >= E) return;
    int r = row[e], c = col[e];
    int pos = atomicAdd(&cursor[c], 1);
    src[pos] = r;
    val[pos] = dinv[r] * w[e] * dinv[c];
}

// ---------------- APPNP hop: one wave per node ----------------------------
__global__ __launch_bounds__(256) void appnp_hop(
    const float* __restrict__ hcur, const float* __restrict__ h0,
    float* __restrict__ hnext, const int* __restrict__ off,
    const int* __restrict__ src, const float* __restrict__ val, int N)
{
    int n = blockIdx.x * 4 + threadIdx.y;
    if (n >= N) return;
    int lane = threadIdx.x;
    int s = off[n], e = off[n + 1];
    float a0 = 0.f, a1 = 0.f;
    for (int i = s; i < e; ++i) {
        int sc = src[i];
        float v = val[i];
        const float* hp = hcur + (size_t)sc * 128;
        a0 += v * hp[lane];
        a1 += v * hp[lane + 64];
    }
    size_t o = (size_t)n * 128;
    hnext[o + lane]      = (1.f - ALPHA) * a0 + ALPHA * h0[o + lane];
    hnext[o + 64 + lane] = (1.f - ALPHA) * a1 + ALPHA * h0[o + 64 + lane];
}

// ---------------- BatchNorm ------------------------------------------------
__global__ __launch_bounds__(256) void bn_reduce(
    const float* __restrict__ h, float* __restrict__ sum,
    float* __restrict__ sumsq, int N)
{
    int f = threadIdx.x & 127;
    int half = threadIdx.x >> 7;
    float s = 0.f, ss = 0.f;
    for (int n = blockIdx.x * 2 + half; n < N; n += 512) {
        float v = h[(size_t)n * 128 + f];
        s += v;
        ss += v * v;
    }
    __shared__ float bufs[256], bufss[256];
    bufs[threadIdx.x] = s;
    bufss[threadIdx.x] = ss;
    __syncthreads();
    if (half == 0) {
        atomicAdd(&sum[f], bufs[f] + bufs[f + 128]);
        atomicAdd(&sumsq[f], bufss[f] + bufss[f + 128]);
    }
}

__global__ void bn_apply(const float* __restrict__ h, const float* __restrict__ sum,
                         const float* __restrict__ sumsq, const float* __restrict__ gamma,
                         const float* __restrict__ beta, float* __restrict__ nodex, int N)
{
    int idx = blockIdx.x * 256 + threadIdx.x;
    if (idx >= N * 128) return;
    int f = idx & 127;
    float invN = 1.f / (float)N;
    float mean = sum[f] * invN;
    float var = sumsq[f] * invN - mean * mean;
    float inv = rsqrtf(var + BN_EPS);
    nodex[idx] = gamma[f] * (h[idx] - mean) * inv + beta[f];
}

// ---------------- pooling boundaries (batch is sorted) ---------------------
__global__ void graph_bounds(const int* __restrict__ batch, int* __restrict__ off_g,
                             int N, int G)
{
    int g = blockIdx.x * blockDim.x + threadIdx.x;
    if (g > G) return;
    int lo = 0, hi = N;
    while (lo < hi) {
        int mid = (lo + hi) >> 1;
        if (batch[mid] < g) lo = mid + 1; else hi = mid;
    }
    off_g[g] = lo;
}

// ---------------- pool + MLP: one block per graph --------------------------
__global__ __launch_bounds__(128) void pool_mlp(
    const float* __restrict__ nodex, const int* __restrict__ off_g,
    const float* __restrict__ l2w, const float* __restrict__ l2b,
    const float* __restrict__ l3w, const float* __restrict__ l3b,
    float* __restrict__ pred, int G)
{
    int g = blockIdx.x;
    int t = threadIdx.x;
    int s = off_g[g], e = off_g[g + 1];
    float acc = 0.f;
    for (int n = s; n < e; ++n) acc += nodex[(size_t)n * 128 + t];
    float cnt = (float)(e - s);
    __shared__ float gx[128];
    __shared__ float hid[64];
    gx[t] = acc / fmaxf(cnt, 1.f);
    __syncthreads();
    if (t < 64) {
        float a = l2b[t];
        const float* w = l2w + t * 128;
        #pragma unroll 8
        for (int k = 0; k < 128; ++k) a += w[k] * gx[k];
        hid[t] = fmaxf(a, 0.f);
    }
    __syncthreads();
    if (t < 5) {
        float a = l3b[t];
        const float* w = l3w + t * 64;
        for (int k = 0; k < 64; ++k) a += w[k] * hid[k];
        pred[g * 5 + t] = a;
    }
}

// ---------------------------------------------------------------------------
extern "C" void kernel_launch(void* const* d_in, const int* in_sizes, int n_in,
                              void* d_out, int out_size, void* d_ws, size_t ws_size,
                              hipStream_t stream)
{
    const float* x      = (const float*)d_in[0];
    const int*   eidx   = (const int*)d_in[1];
    const float* eattr  = (const float*)d_in[2];
    const int*   batch  = (const int*)d_in[3];
    const float* c1w    = (const float*)d_in[5];
    const float* c1b    = (const float*)d_in[6];
    const float* c2w    = (const float*)d_in[7];
    const float* c2b    = (const float*)d_in[8];
    const float* l1w    = (const float*)d_in[9];
    const float* l1b    = (const float*)d_in[10];
    const float* gamma  = (const float*)d_in[11];
    const float* beta   = (const float*)d_in[12];
    const float* l2w    = (const float*)d_in[13];
    const float* l2b    = (const float*)d_in[14];
    const float* l3w    = (const float*)d_in[15];
    const float* l3b    = (const float*)d_in[16];

    const int N = in_sizes[3];
    const int E = in_sizes[2];
    const int G = (out_size - N * 128) / 5;

    const int* erow = eidx;       // edge_index[0]
    const int* ecol = eidx + E;   // edge_index[1]

    // ---- workspace carve-up ----
    char* p = (char*)d_ws;
    auto alloc = [&](size_t bytes) -> void* {
        void* r = (void*)p;
        p += (bytes + 255) & ~(size_t)255;
        return r;
    };
    float* h2     = (float*)alloc((size_t)N * 245 * sizeof(float));
    float* h0     = (float*)alloc((size_t)N * 128 * sizeof(float));
    float* hA     = (float*)alloc((size_t)N * 128 * sizeof(float));
    float* hB     = (float*)alloc((size_t)N * 128 * sizeof(float));
    float* deg    = (float*)alloc((size_t)N * sizeof(float));
    float* dinv   = (float*)alloc((size_t)N * sizeof(float));
    float* bnsum  = (float*)alloc(256 * sizeof(float)); // sum[128] + sumsq[128]
    float* bnssq  = bnsum + 128;
    float* val    = (float*)alloc((size_t)E * sizeof(float));
    int*   cnt    = (int*)alloc((size_t)N * sizeof(int));
    int*   off    = (int*)alloc((size_t)(N + 1) * sizeof(int));
    int*   cursor = (int*)alloc((size_t)N * sizeof(int));
    int*   srcarr = (int*)alloc((size_t)E * sizeof(int));
    int*   off_g  = (int*)alloc((size_t)(G + 1) * sizeof(int));

    float* pred  = (float*)d_out;
    float* nodex = (float*)d_out + (size_t)G * 5;

    // ---- zero-init accumulators (ws is poisoned before every call) ----
    hipMemsetAsync(deg, 0, (size_t)N * sizeof(float), stream);
    hipMemsetAsync(cnt, 0, (size_t)N * sizeof(int), stream);
    hipMemsetAsync(bnsum, 0, 256 * sizeof(float), stream);

    // ---- CNN encoder ----
    conv_fused<<<N, 256, 0, stream>>>(x, c1w, c1b, c2w, c2b, h2, N);
    l1_kernel<<<(N + 63) / 64, 256, 0, stream>>>(h2, l1w, l1b, h0, N);

    // ---- edge normalization + CSR build ----
    int egrid = (E + 255) / 256;
    deg_kernel<<<egrid, 256, 0, stream>>>(ecol, eattr, deg, E);
    cnt_kernel<<<egrid, 256, 0, stream>>>(ecol, cnt, E);
    dinv_kernel<<<(N + 255) / 256, 256, 0, stream>>>(deg, dinv, N);
    scan_kernel<<<1, 1024, 0, stream>>>(cnt, off, cursor, N);
    scatter_edges<<<egrid, 256, 0, stream>>>(erow, ecol, eattr, dinv, cursor,
                                             srcarr, val, E);

    // ---- APPNP hops ----
    dim3 hopblk(64, 4);
    int hopgrid = (N + 3) / 4;
    appnp_hop<<<hopgrid, hopblk, 0, stream>>>(h0, h0, hA, off, srcarr, val, N);
    appnp_hop<<<hopgrid, hopblk, 0, stream>>>(hA, h0, hB, off, srcarr, val, N);

    // ---- BatchNorm ----
    bn_reduce<<<256, 256, 0, stream>>>(hB, bnsum, bnssq, N);
    bn_apply<<<(N * 128 + 255) / 256, 256, 0, stream>>>(hB, bnsum, bnssq, gamma,
                                                        beta, nodex, N);

    // ---- pool + MLP ----
    graph_bounds<<<(G + 1 + 255) / 256, 256, 0, stream>>>(batch, off_g, N, G);
    pool_mlp<<<G, 128, 0, stream>>>(nodex, off_g, l2w, l2b, l3w, l3b, pred, G);
}

// Round 2
// 1440.859 us; speedup vs baseline: 1.6369x; 1.6369x over previous
//
#include <hip/hip_runtime.h>
#include <hip/hip_bf16.h>

// ---------------------------------------------------------------------------
// VGNet: conv1(3->8,3x3,s1)+relu -> conv2(8->5,5x5,s2)+relu -> flatten(245)
//        -> l1(245->128)+relu -> APPNP(K=2, alpha=0.8) -> BatchNorm ->
//        mean-pool by graph -> MLP(128->64->5)
// Outputs: pred [G,5] then node_x [N,128], concatenated in d_out (fp32).
// ---------------------------------------------------------------------------

#define ALPHA 0.8f
#define BN_EPS 1e-5f

// ---------------- CNN encoder: conv1 + conv2 fused, one node per block -----
// Register-blocked: weights via wave-uniform global reads (s_load / scalar
// cache), x-values in VGPRs, one thread = one output pixel, all channels.
__global__ __launch_bounds__(320) void conv_fused(
    const float* __restrict__ x,
    const float* __restrict__ c1w, const float* __restrict__ c1b,
    const float* __restrict__ c2w, const float* __restrict__ c2b,
    float* __restrict__ h2out, int N)
{
    __shared__ float xs[3 * 19 * 19];   // 1083
    __shared__ float h1[8 * 17 * 17];   // 2312

    int n = blockIdx.x;
    int t = threadIdx.x;
    const float* xp = x + (size_t)n * 1083;
    for (int i = t; i < 1083; i += 320) xs[i] = xp[i];
    __syncthreads();

    // conv1: out [8][17][17], 3x3, stride 1, relu. Thread t<289 -> pixel.
    if (t < 289) {
        int y = t / 17;
        int xx = t % 17;
        float xv[27];
        #pragma unroll
        for (int ci = 0; ci < 3; ++ci)
            #pragma unroll
            for (int ky = 0; ky < 3; ++ky)
                #pragma unroll
                for (int kx = 0; kx < 3; ++kx)
                    xv[ci * 9 + ky * 3 + kx] = xs[ci * 361 + (y + ky) * 19 + xx + kx];
        #pragma unroll
        for (int o = 0; o < 8; ++o) {
            float acc = c1b[o];                 // uniform -> scalar load
            #pragma unroll
            for (int j = 0; j < 27; ++j)
                acc += xv[j] * c1w[o * 27 + j]; // uniform -> scalar load
            h1[o * 289 + t] = fmaxf(acc, 0.f);
        }
    }
    __syncthreads();

    // conv2: out [5][7][7], 5x5, stride 2, relu. Thread t<49 -> pixel, 5 ch.
    if (t < 49) {
        int y = t / 7;
        int xx = t % 7;
        float acc[5];
        #pragma unroll
        for (int o = 0; o < 5; ++o) acc[o] = c2b[o];
        #pragma unroll
        for (int ci = 0; ci < 8; ++ci) {
            float hv[25];
            #pragma unroll
            for (int ky = 0; ky < 5; ++ky)
                #pragma unroll
                for (int kx = 0; kx < 5; ++kx)
                    hv[ky * 5 + kx] = h1[ci * 289 + (2 * y + ky) * 17 + 2 * xx + kx];
            #pragma unroll
            for (int o = 0; o < 5; ++o) {
                const float* wp = c2w + o * 200 + ci * 25; // uniform
                #pragma unroll
                for (int j = 0; j < 25; ++j)
                    acc[o] += hv[j] * wp[j];
            }
        }
        #pragma unroll
        for (int o = 0; o < 5; ++o)
            h2out[(size_t)n * 245 + o * 49 + t] = fmaxf(acc[o], 0.f);
    }
}

// ---------------- weight transpose for l1: wT[245][128] --------------------
__global__ void transpose_w(const float* __restrict__ w, float* __restrict__ wT)
{
    int idx = blockIdx.x * 256 + threadIdx.x;
    if (idx >= 128 * 245) return;
    int f = idx / 245, k = idx % 245;
    wT[k * 128 + f] = w[idx];
}

// ---------------- l1: h0[N,128] = relu(h2[N,245] @ l1w.T + l1b) ------------
// 64-node tile in LDS; thread (fg=t&31, ng=t>>5) computes an 8-node x 4-feat
// register tile: 32 FMAs per (8 LDS broadcast reads + 1 coalesced float4).
__global__ __launch_bounds__(256) void l1_kernel(
    const float* __restrict__ h2, const float* __restrict__ wT,
    const float* __restrict__ l1b, float* __restrict__ h0, int N)
{
    __shared__ float hs[64 * 245]; // 62.7 KB
    int t = threadIdx.x;
    int n0 = blockIdx.x * 64;
    int count = min(64, N - n0);
    int tot = count * 245;
    for (int i = t; i < 64 * 245; i += 256)
        hs[i] = (i < tot) ? h2[(size_t)n0 * 245 + i] : 0.f;
    __syncthreads();

    int fg = t & 31;   // feature group: feats fg*4 .. fg*4+3
    int ng = t >> 5;   // node group:   nodes ng*8 .. ng*8+7
    float acc[8][4];
    #pragma unroll
    for (int j = 0; j < 8; ++j)
        #pragma unroll
        for (int i = 0; i < 4; ++i) acc[j][i] = 0.f;

    for (int k = 0; k < 245; ++k) {
        float4 w4 = *(const float4*)&wT[k * 128 + fg * 4];
        float a[8];
        #pragma unroll
        for (int j = 0; j < 8; ++j) a[j] = hs[(ng * 8 + j) * 245 + k];
        #pragma unroll
        for (int j = 0; j < 8; ++j) {
            acc[j][0] += a[j] * w4.x;
            acc[j][1] += a[j] * w4.y;
            acc[j][2] += a[j] * w4.z;
            acc[j][3] += a[j] * w4.w;
        }
    }
    float4 b4 = *(const float4*)&l1b[fg * 4];
    #pragma unroll
    for (int j = 0; j < 8; ++j) {
        int nloc = ng * 8 + j;
        int nn = n0 + nloc;
        if (nn < N) {
            float4 r;
            r.x = fmaxf(acc[j][0] + b4.x, 0.f);
            r.y = fmaxf(acc[j][1] + b4.y, 0.f);
            r.z = fmaxf(acc[j][2] + b4.z, 0.f);
            r.w = fmaxf(acc[j][3] + b4.w, 0.f);
            *(float4*)&h0[(size_t)nn * 128 + fg * 4] = r;
        }
    }
}

// ---------------- graph-normalization prep --------------------------------
__global__ void deg_cnt_kernel(const int* __restrict__ col, const float* __restrict__ w,
                               float* __restrict__ deg, int* __restrict__ cnt, int E)
{
    int e = blockIdx.x * 256 + threadIdx.x;
    if (e < E) {
        int c = col[e];
        atomicAdd(&deg[c], w[e]);
        atomicAdd(&cnt[c], 1);
    }
}

__global__ void dinv_kernel(const float* __restrict__ deg, float* __restrict__ dinv, int N)
{
    int n = blockIdx.x * 256 + threadIdx.x;
    if (n < N) {
        float d = deg[n];
        dinv[n] = d > 0.f ? rsqrtf(d) : 0.f;
    }
}

// single-block exclusive scan over cnt[N] -> off[N+1]; also copies to cursor
__global__ __launch_bounds__(1024) void scan_kernel(
    const int* __restrict__ cnt, int* __restrict__ off,
    int* __restrict__ cursor, int N)
{
    __shared__ int buf[1024];
    __shared__ int carry;
    if (threadIdx.x == 0) carry = 0;
    __syncthreads();
    for (int base = 0; base < N; base += 1024) {
        int i = base + threadIdx.x;
        int v = (i < N) ? cnt[i] : 0;
        buf[threadIdx.x] = v;
        __syncthreads();
        for (int ofs = 1; ofs < 1024; ofs <<= 1) {
            int tmp = (threadIdx.x >= ofs) ? buf[threadIdx.x - ofs] : 0;
            __syncthreads();
            buf[threadIdx.x] += tmp;
            __syncthreads();
        }
        int incl = buf[threadIdx.x];
        if (i < N) {
            int excl = carry + incl - v;
            off[i] = excl;
            cursor[i] = excl;
        }
        int total = buf[1023];
        __syncthreads();
        if (threadIdx.x == 0) carry += total;
        __syncthreads();
    }
    if (threadIdx.x == 0) off[N] = carry;
}

__global__ void scatter_edges(const int* __restrict__ row, const int* __restrict__ col,
                              const float* __restrict__ w, const float* __restrict__ dinv,
                              int* __restrict__ cursor, int* __restrict__ src,
                              float* __restrict__ val, int E)
{
    int e = blockIdx.x * 256 + threadIdx.x;
    if (e >= E) return;
    int r = row[e], c = col[e];
    int pos = atomicAdd(&cursor[c], 1);
    src[pos] = r;
    val[pos] = dinv[r] * w[e] * dinv[c];
}

// ---------------- APPNP hop: one wave per node ----------------------------
__global__ __launch_bounds__(256) void appnp_hop(
    const float* __restrict__ hcur, const float* __restrict__ h0,
    float* __restrict__ hnext, const int* __restrict__ off,
    const int* __restrict__ src, const float* __restrict__ val, int N)
{
    int n = blockIdx.x * 4 + threadIdx.y;
    if (n >= N) return;
    int lane = threadIdx.x;
    int s = off[n], e = off[n + 1];
    float a0 = 0.f, a1 = 0.f;
    for (int i = s; i < e; ++i) {
        int sc = src[i];
        float v = val[i];
        const float* hp = hcur + (size_t)sc * 128;
        a0 += v * hp[lane];
        a1 += v * hp[lane + 64];
    }
    size_t o = (size_t)n * 128;
    hnext[o + lane]      = (1.f - ALPHA) * a0 + ALPHA * h0[o + lane];
    hnext[o + 64 + lane] = (1.f - ALPHA) * a1 + ALPHA * h0[o + 64 + lane];
}

// ---------------- BatchNorm ------------------------------------------------
__global__ __launch_bounds__(256) void bn_reduce(
    const float* __restrict__ h, float* __restrict__ sum,
    float* __restrict__ sumsq, int N)
{
    int f = threadIdx.x & 127;
    int half = threadIdx.x >> 7;
    float s = 0.f, ss = 0.f;
    for (int n = blockIdx.x * 2 + half; n < N; n += 512) {
        float v = h[(size_t)n * 128 + f];
        s += v;
        ss += v * v;
    }
    __shared__ float bufs[256], bufss[256];
    bufs[threadIdx.x] = s;
    bufss[threadIdx.x] = ss;
    __syncthreads();
    if (half == 0) {
        atomicAdd(&sum[f], bufs[f] + bufs[f + 128]);
        atomicAdd(&sumsq[f], bufss[f] + bufss[f + 128]);
    }
}

__global__ void bn_apply(const float* __restrict__ h, const float* __restrict__ sum,
                         const float* __restrict__ sumsq, const float* __restrict__ gamma,
                         const float* __restrict__ beta, float* __restrict__ nodex, int N)
{
    int idx = blockIdx.x * 256 + threadIdx.x;
    if (idx >= N * 128) return;
    int f = idx & 127;
    float invN = 1.f / (float)N;
    float mean = sum[f] * invN;
    float var = sumsq[f] * invN - mean * mean;
    float inv = rsqrtf(var + BN_EPS);
    nodex[idx] = gamma[f] * (h[idx] - mean) * inv + beta[f];
}

// ---------------- pooling boundaries (batch is sorted) ---------------------
__global__ void graph_bounds(const int* __restrict__ batch, int* __restrict__ off_g,
                             int N, int G)
{
    int g = blockIdx.x * blockDim.x + threadIdx.x;
    if (g > G) return;
    int lo = 0, hi = N;
    while (lo < hi) {
        int mid = (lo + hi) >> 1;
        if (batch[mid] < g) lo = mid + 1; else hi = mid;
    }
    off_g[g] = lo;
}

// ---------------- pool + MLP: one block per graph --------------------------
__global__ __launch_bounds__(128) void pool_mlp(
    const float* __restrict__ nodex, const int* __restrict__ off_g,
    const float* __restrict__ l2w, const float* __restrict__ l2b,
    const float* __restrict__ l3w, const float* __restrict__ l3b,
    float* __restrict__ pred, int G)
{
    int g = blockIdx.x;
    int t = threadIdx.x;
    int s = off_g[g], e = off_g[g + 1];
    float acc = 0.f;
    for (int n = s; n < e; ++n) acc += nodex[(size_t)n * 128 + t];
    float cnt = (float)(e - s);
    __shared__ float gx[128];
    __shared__ float hid[64];
    gx[t] = acc / fmaxf(cnt, 1.f);
    __syncthreads();
    if (t < 64) {
        float a = l2b[t];
        const float* w = l2w + t * 128;
        #pragma unroll 8
        for (int k = 0; k < 128; ++k) a += w[k] * gx[k];
        hid[t] = fmaxf(a, 0.f);
    }
    __syncthreads();
    if (t < 5) {
        float a = l3b[t];
        const float* w = l3w + t * 64;
        for (int k = 0; k < 64; ++k) a += w[k] * hid[k];
        pred[g * 5 + t] = a;
    }
}

// ---------------------------------------------------------------------------
extern "C" void kernel_launch(void* const* d_in, const int* in_sizes, int n_in,
                              void* d_out, int out_size, void* d_ws, size_t ws_size,
                              hipStream_t stream)
{
    const float* x      = (const float*)d_in[0];
    const int*   eidx   = (const int*)d_in[1];
    const float* eattr  = (const float*)d_in[2];
    const int*   batch  = (const int*)d_in[3];
    const float* c1w    = (const float*)d_in[5];
    const float* c1b    = (const float*)d_in[6];
    const float* c2w    = (const float*)d_in[7];
    const float* c2b    = (const float*)d_in[8];
    const float* l1w    = (const float*)d_in[9];
    const float* l1b    = (const float*)d_in[10];
    const float* gamma  = (const float*)d_in[11];
    const float* beta   = (const float*)d_in[12];
    const float* l2w    = (const float*)d_in[13];
    const float* l2b    = (const float*)d_in[14];
    const float* l3w    = (const float*)d_in[15];
    const float* l3b    = (const float*)d_in[16];

    const int N = in_sizes[3];
    const int E = in_sizes[2];
    const int G = (out_size - N * 128) / 5;

    const int* erow = eidx;       // edge_index[0]
    const int* ecol = eidx + E;   // edge_index[1]

    // ---- workspace carve-up ----
    char* p = (char*)d_ws;
    auto alloc = [&](size_t bytes) -> void* {
        void* r = (void*)p;
        p += (bytes + 255) & ~(size_t)255;
        return r;
    };
    float* h2     = (float*)alloc((size_t)N * 245 * sizeof(float));
    float* h0     = (float*)alloc((size_t)N * 128 * sizeof(float));
    float* hA     = (float*)alloc((size_t)N * 128 * sizeof(float));
    float* hB     = (float*)alloc((size_t)N * 128 * sizeof(float));
    float* deg    = (float*)alloc((size_t)N * sizeof(float));
    float* dinv   = (float*)alloc((size_t)N * sizeof(float));
    float* bnsum  = (float*)alloc(256 * sizeof(float)); // sum[128] + sumsq[128]
    float* bnssq  = bnsum + 128;
    float* val    = (float*)alloc((size_t)E * sizeof(float));
    float* wT     = (float*)alloc((size_t)245 * 128 * sizeof(float));
    int*   cnt    = (int*)alloc((size_t)N * sizeof(int));
    int*   off    = (int*)alloc((size_t)(N + 1) * sizeof(int));
    int*   cursor = (int*)alloc((size_t)N * sizeof(int));
    int*   srcarr = (int*)alloc((size_t)E * sizeof(int));
    int*   off_g  = (int*)alloc((size_t)(G + 1) * sizeof(int));

    float* pred  = (float*)d_out;
    float* nodex = (float*)d_out + (size_t)G * 5;

    // ---- zero-init accumulators (ws is poisoned before every call) ----
    hipMemsetAsync(deg, 0, (size_t)N * sizeof(float), stream);
    hipMemsetAsync(cnt, 0, (size_t)N * sizeof(int), stream);
    hipMemsetAsync(bnsum, 0, 256 * sizeof(float), stream);

    // ---- CNN encoder ----
    conv_fused<<<N, 320, 0, stream>>>(x, c1w, c1b, c2w, c2b, h2, N);
    transpose_w<<<(128 * 245 + 255) / 256, 256, 0, stream>>>(l1w, wT);
    l1_kernel<<<(N + 63) / 64, 256, 0, stream>>>(h2, wT, l1b, h0, N);

    // ---- edge normalization + CSR build ----
    int egrid = (E + 255) / 256;
    deg_cnt_kernel<<<egrid, 256, 0, stream>>>(ecol, eattr, deg, cnt, E);
    dinv_kernel<<<(N + 255) / 256, 256, 0, stream>>>(deg, dinv, N);
    scan_kernel<<<1, 1024, 0, stream>>>(cnt, off, cursor, N);
    scatter_edges<<<egrid, 256, 0, stream>>>(erow, ecol, eattr, dinv, cursor,
                                             srcarr, val, E);

    // ---- APPNP hops ----
    dim3 hopblk(64, 4);
    int hopgrid = (N + 3) / 4;
    appnp_hop<<<hopgrid, hopblk, 0, stream>>>(h0, h0, hA, off, srcarr, val, N);
    appnp_hop<<<hopgrid, hopblk, 0, stream>>>(hA, h0, hB, off, srcarr, val, N);

    // ---- BatchNorm ----
    bn_reduce<<<256, 256, 0, stream>>>(hB, bnsum, bnssq, N);
    bn_apply<<<(N * 128 + 255) / 256, 256, 0, stream>>>(hB, bnsum, bnssq, gamma,
                                                        beta, nodex, N);

    // ---- pool + MLP ----
    graph_bounds<<<(G + 1 + 255) / 256, 256, 0, stream>>>(batch, off_g, N, G);
    pool_mlp<<<G, 128, 0, stream>>>(nodex, off_g, l2w, l2b, l3w, l3b, pred, G);
}

// Round 3
// 1143.489 us; speedup vs baseline: 2.0626x; 1.2601x over previous
//
#include <hip/hip_runtime.h>
#include <hip/hip_bf16.h>

// ---------------------------------------------------------------------------
// VGNet: conv1(3->8,3x3,s1)+relu -> conv2(8->5,5x5,s2)+relu -> flatten(245)
//        -> l1(245->128)+relu -> APPNP(K=2, alpha=0.8) -> BatchNorm ->
//        mean-pool by graph -> MLP(128->64->5)
// Outputs: pred [G,5] then node_x [N,128], concatenated in d_out (fp32).
// h through the APPNP chain is stored bf16 (2 feats packed per uint).
// ---------------------------------------------------------------------------

#define ALPHA 0.8f
#define BN_EPS 1e-5f

typedef unsigned int uint32;
typedef unsigned short ushort16;

__device__ __forceinline__ float bflo(uint32 g) { return __uint_as_float(g << 16); }
__device__ __forceinline__ float bfhi(uint32 g) { return __uint_as_float(g & 0xffff0000u); }
__device__ __forceinline__ ushort16 f2bfu(float f) {
    __hip_bfloat16 b = __float2bfloat16(f);
    union { __hip_bfloat16 b; ushort16 u; } c; c.b = b; return c.u;
}

// ---------------- CNN encoder: conv1 + conv2 fused, one node per block -----
// min 4 waves/EU -> VGPR cap 128 so xv[27]/hv[25] stay in registers
// (R2's VGPR_Count=24 showed the compiler was re-reading LDS per channel).
__global__ __launch_bounds__(320, 4) void conv_fused(
    const float* __restrict__ x,
    const float* __restrict__ c1w, const float* __restrict__ c1b,
    const float* __restrict__ c2w, const float* __restrict__ c2b,
    float* __restrict__ h2out, int N)
{
    __shared__ float xs[3 * 19 * 19];   // 1083
    __shared__ float h1[8 * 17 * 17];   // 2312

    int n = blockIdx.x;
    int t = threadIdx.x;
    const float* xp = x + (size_t)n * 1083;
    for (int i = t; i < 1083; i += 320) xs[i] = xp[i];
    __syncthreads();

    // conv1: out [8][17][17], 3x3, stride 1, relu. Thread t<289 -> pixel.
    if (t < 289) {
        int y = t / 17;
        int xx = t % 17;
        float xv[27];
        #pragma unroll
        for (int ci = 0; ci < 3; ++ci)
            #pragma unroll
            for (int ky = 0; ky < 3; ++ky)
                #pragma unroll
                for (int kx = 0; kx < 3; ++kx)
                    xv[ci * 9 + ky * 3 + kx] = xs[ci * 361 + (y + ky) * 19 + xx + kx];
        #pragma unroll
        for (int o = 0; o < 8; ++o) {
            float acc = c1b[o];                 // uniform -> scalar load
            #pragma unroll
            for (int j = 0; j < 27; ++j)
                acc += xv[j] * c1w[o * 27 + j]; // uniform -> scalar load
            h1[o * 289 + t] = fmaxf(acc, 0.f);
        }
    }
    __syncthreads();

    // conv2: out [5][7][7], 5x5, stride 2, relu. Thread t<49 -> pixel, 5 ch.
    if (t < 49) {
        int y = t / 7;
        int xx = t % 7;
        float acc[5];
        #pragma unroll
        for (int o = 0; o < 5; ++o) acc[o] = c2b[o];
        #pragma unroll
        for (int ci = 0; ci < 8; ++ci) {
            float hv[25];
            #pragma unroll
            for (int ky = 0; ky < 5; ++ky)
                #pragma unroll
                for (int kx = 0; kx < 5; ++kx)
                    hv[ky * 5 + kx] = h1[ci * 289 + (2 * y + ky) * 17 + 2 * xx + kx];
            #pragma unroll
            for (int o = 0; o < 5; ++o) {
                const float* wp = c2w + o * 200 + ci * 25; // uniform -> scalar
                #pragma unroll
                for (int j = 0; j < 25; ++j)
                    acc[o] += hv[j] * wp[j];
            }
        }
        #pragma unroll
        for (int o = 0; o < 5; ++o)
            h2out[(size_t)n * 245 + o * 49 + t] = fmaxf(acc[o], 0.f);
    }
}

// ---------------- weight transpose for l1: wT[245][128] --------------------
__global__ void transpose_w(const float* __restrict__ w, float* __restrict__ wT)
{
    int idx = blockIdx.x * 256 + threadIdx.x;
    if (idx >= 128 * 245) return;
    int f = idx / 245, k = idx % 245;
    wT[k * 128 + f] = w[idx];
}

// ---------------- l1: h0[N,128] = relu(h2[N,245] @ l1w.T + l1b), bf16 out --
__global__ __launch_bounds__(256, 2) void l1_kernel(
    const float* __restrict__ h2, const float* __restrict__ wT,
    const float* __restrict__ l1b, ushort16* __restrict__ h0, int N)
{
    __shared__ float hs[64 * 245]; // 62.7 KB
    int t = threadIdx.x;
    int n0 = blockIdx.x * 64;
    int count = min(64, N - n0);
    int tot = count * 245;
    for (int i = t; i < 64 * 245; i += 256)
        hs[i] = (i < tot) ? h2[(size_t)n0 * 245 + i] : 0.f;
    __syncthreads();

    int fg = t & 31;   // feature group: feats fg*4 .. fg*4+3
    int ng = t >> 5;   // node group:   nodes ng*8 .. ng*8+7
    float acc[8][4];
    #pragma unroll
    for (int j = 0; j < 8; ++j)
        #pragma unroll
        for (int i = 0; i < 4; ++i) acc[j][i] = 0.f;

    for (int k = 0; k < 245; ++k) {
        float4 w4 = *(const float4*)&wT[k * 128 + fg * 4];
        float a[8];
        #pragma unroll
        for (int j = 0; j < 8; ++j) a[j] = hs[(ng * 8 + j) * 245 + k];
        #pragma unroll
        for (int j = 0; j < 8; ++j) {
            acc[j][0] += a[j] * w4.x;
            acc[j][1] += a[j] * w4.y;
            acc[j][2] += a[j] * w4.z;
            acc[j][3] += a[j] * w4.w;
        }
    }
    float4 b4 = *(const float4*)&l1b[fg * 4];
    #pragma unroll
    for (int j = 0; j < 8; ++j) {
        int nn = n0 + ng * 8 + j;
        if (nn < N) {
            ushort4 r;
            r.x = f2bfu(fmaxf(acc[j][0] + b4.x, 0.f));
            r.y = f2bfu(fmaxf(acc[j][1] + b4.y, 0.f));
            r.z = f2bfu(fmaxf(acc[j][2] + b4.z, 0.f));
            r.w = f2bfu(fmaxf(acc[j][3] + b4.w, 0.f));
            *(ushort4*)&h0[(size_t)nn * 128 + fg * 4] = r;
        }
    }
}

// ---------------- graph-normalization prep --------------------------------
__global__ void deg_cnt_kernel(const int* __restrict__ col, const float* __restrict__ w,
                               float* __restrict__ deg, int* __restrict__ cnt, int E)
{
    int e = blockIdx.x * 256 + threadIdx.x;
    if (e < E) {
        int c = col[e];
        atomicAdd(&deg[c], w[e]);
        atomicAdd(&cnt[c], 1);
    }
}

__global__ void dinv_kernel(const float* __restrict__ deg, float* __restrict__ dinv, int N)
{
    int n = blockIdx.x * 256 + threadIdx.x;
    if (n < N) {
        float d = deg[n];
        dinv[n] = d > 0.f ? rsqrtf(d) : 0.f;
    }
}

// ---------------- multi-block exclusive scan of cnt[N] ---------------------
// k1: per-block (1024 elems) sums; k2: scan of block sums; k3: write offsets.
__global__ __launch_bounds__(256) void scan_block_sums(
    const int* __restrict__ cnt, int* __restrict__ bsum, int N)
{
    int base = blockIdx.x * 1024 + threadIdx.x * 4;
    int s = 0;
    #pragma unroll
    for (int k = 0; k < 4; ++k) { int i = base + k; if (i < N) s += cnt[i]; }
    __shared__ int red[256];
    red[threadIdx.x] = s;
    __syncthreads();
    for (int ofs = 128; ofs > 0; ofs >>= 1) {
        if (threadIdx.x < ofs) red[threadIdx.x] += red[threadIdx.x + ofs];
        __syncthreads();
    }
    if (threadIdx.x == 0) bsum[blockIdx.x] = red[0];
}

__global__ __launch_bounds__(256) void scan_block_offsets(
    const int* __restrict__ bsum, int* __restrict__ boff, int B,
    int* __restrict__ off_last, int E)
{
    __shared__ int buf[256];
    __shared__ int carry;
    if (threadIdx.x == 0) carry = 0;
    __syncthreads();
    for (int base = 0; base < B; base += 256) {
        int i = base + threadIdx.x;
        int v = (i < B) ? bsum[i] : 0;
        buf[threadIdx.x] = v;
        __syncthreads();
        for (int ofs = 1; ofs < 256; ofs <<= 1) {
            int add = (threadIdx.x >= ofs) ? buf[threadIdx.x - ofs] : 0;
            __syncthreads();
            buf[threadIdx.x] += add;
            __syncthreads();
        }
        if (i < B) boff[i] = carry + buf[threadIdx.x] - v;
        int tot = buf[255];
        __syncthreads();
        if (threadIdx.x == 0) carry += tot;
        __syncthreads();
    }
    if (threadIdx.x == 0) *off_last = E;
}

__global__ __launch_bounds__(256) void scan_write(
    const int* __restrict__ cnt, const int* __restrict__ boff,
    int* __restrict__ off, int* __restrict__ cursor, int N)
{
    int base = blockIdx.x * 1024 + threadIdx.x * 4;
    int v[4];
    #pragma unroll
    for (int k = 0; k < 4; ++k) { int i = base + k; v[k] = (i < N) ? cnt[i] : 0; }
    int tsum = v[0] + v[1] + v[2] + v[3];
    __shared__ int buf[256];
    buf[threadIdx.x] = tsum;
    __syncthreads();
    for (int ofs = 1; ofs < 256; ofs <<= 1) {
        int add = (threadIdx.x >= ofs) ? buf[threadIdx.x - ofs] : 0;
        __syncthreads();
        buf[threadIdx.x] += add;
        __syncthreads();
    }
    int excl = boff[blockIdx.x] + buf[threadIdx.x] - tsum;
    #pragma unroll
    for (int k = 0; k < 4; ++k) {
        int i = base + k;
        if (i < N) { off[i] = excl; cursor[i] = excl; excl += v[k]; }
    }
}

// ---------------- CSR edge scatter: packed {src-bits, val} -----------------
__global__ void scatter_edges(const int* __restrict__ row, const int* __restrict__ col,
                              const float* __restrict__ w, const float* __restrict__ dinv,
                              int* __restrict__ cursor, float2* __restrict__ edges, int E)
{
    int e = blockIdx.x * 256 + threadIdx.x;
    if (e >= E) return;
    int r = row[e], c = col[e];
    int pos = atomicAdd(&cursor[c], 1);
    edges[pos] = make_float2(__int_as_float(r), dinv[r] * w[e] * dinv[c]);
}

// ---------------- APPNP hop: one wave per node, bf16 h, fp32 accumulate ----
__global__ __launch_bounds__(256) void appnp_hop(
    const uint32* __restrict__ hcur, const uint32* __restrict__ h0,
    uint32* __restrict__ hnext, const int* __restrict__ off,
    const float2* __restrict__ edges, int N)
{
    int n = blockIdx.x * 4 + threadIdx.y;
    if (n >= N) return;
    int lane = threadIdx.x;
    int s = off[n], e = off[n + 1];
    float a0 = 0.f, a1 = 0.f, b0 = 0.f, b1 = 0.f;
    float c0 = 0.f, c1 = 0.f, d0 = 0.f, d1 = 0.f;
    int i = s;
    for (; i + 3 < e; i += 4) {
        float2 e0 = edges[i], e1 = edges[i + 1], e2 = edges[i + 2], e3 = edges[i + 3];
        uint32 g0 = hcur[((size_t)__float_as_int(e0.x) << 6) + lane];
        uint32 g1 = hcur[((size_t)__float_as_int(e1.x) << 6) + lane];
        uint32 g2 = hcur[((size_t)__float_as_int(e2.x) << 6) + lane];
        uint32 g3 = hcur[((size_t)__float_as_int(e3.x) << 6) + lane];
        a0 += e0.y * bflo(g0); a1 += e0.y * bfhi(g0);
        b0 += e1.y * bflo(g1); b1 += e1.y * bfhi(g1);
        c0 += e2.y * bflo(g2); c1 += e2.y * bfhi(g2);
        d0 += e3.y * bflo(g3); d1 += e3.y * bfhi(g3);
    }
    for (; i < e; ++i) {
        float2 ee = edges[i];
        uint32 g = hcur[((size_t)__float_as_int(ee.x) << 6) + lane];
        a0 += ee.y * bflo(g); a1 += ee.y * bfhi(g);
    }
    float r0 = (a0 + b0) + (c0 + d0);
    float r1 = (a1 + b1) + (c1 + d1);
    uint32 p = h0[((size_t)n << 6) + lane];
    float o0 = (1.f - ALPHA) * r0 + ALPHA * bflo(p);
    float o1 = (1.f - ALPHA) * r1 + ALPHA * bfhi(p);
    hnext[((size_t)n << 6) + lane] = (uint32)f2bfu(o0) | ((uint32)f2bfu(o1) << 16);
}

// ---------------- BatchNorm (bf16 in, fp32 stats, fp32 node_x out) ---------
__global__ __launch_bounds__(256) void bn_reduce(
    const uint32* __restrict__ h, float* __restrict__ sum,
    float* __restrict__ sumsq, int N)
{
    int fp = threadIdx.x & 63;      // feature pair
    int q = threadIdx.x >> 6;       // 0..3
    float s0 = 0.f, ss0 = 0.f, s1 = 0.f, ss1 = 0.f;
    for (int n = blockIdx.x * 4 + q; n < N; n += 1024) {
        uint32 g = h[(size_t)n * 64 + fp];
        float v0 = bflo(g), v1 = bfhi(g);
        s0 += v0; ss0 += v0 * v0;
        s1 += v1; ss1 += v1 * v1;
    }
    __shared__ float b[4][256];
    b[0][threadIdx.x] = s0; b[1][threadIdx.x] = ss0;
    b[2][threadIdx.x] = s1; b[3][threadIdx.x] = ss1;
    __syncthreads();
    if (q == 0) {
        float S0 = 0.f, SS0 = 0.f, S1 = 0.f, SS1 = 0.f;
        #pragma unroll
        for (int k = 0; k < 4; ++k) {
            S0 += b[0][k * 64 + fp]; SS0 += b[1][k * 64 + fp];
            S1 += b[2][k * 64 + fp]; SS1 += b[3][k * 64 + fp];
        }
        atomicAdd(&sum[2 * fp], S0);     atomicAdd(&sumsq[2 * fp], SS0);
        atomicAdd(&sum[2 * fp + 1], S1); atomicAdd(&sumsq[2 * fp + 1], SS1);
    }
}

__global__ void bn_apply(const uint32* __restrict__ h, const float* __restrict__ sum,
                         const float* __restrict__ sumsq, const float* __restrict__ gamma,
                         const float* __restrict__ beta, float2* __restrict__ nodex, int N)
{
    int idx = blockIdx.x * 256 + threadIdx.x; // over N*64 feature-pairs
    if (idx >= N * 64) return;
    int fp = idx & 63;
    float invN = 1.f / (float)N;
    float m0 = sum[2 * fp] * invN, m1 = sum[2 * fp + 1] * invN;
    float v0 = sumsq[2 * fp] * invN - m0 * m0;
    float v1 = sumsq[2 * fp + 1] * invN - m1 * m1;
    float i0 = rsqrtf(v0 + BN_EPS), i1 = rsqrtf(v1 + BN_EPS);
    uint32 g = h[idx];
    float2 out;
    out.x = gamma[2 * fp] * (bflo(g) - m0) * i0 + beta[2 * fp];
    out.y = gamma[2 * fp + 1] * (bfhi(g) - m1) * i1 + beta[2 * fp + 1];
    nodex[idx] = out;
}

// ---------------- pooling boundaries (batch is sorted) ---------------------
__global__ void graph_bounds(const int* __restrict__ batch, int* __restrict__ off_g,
                             int N, int G)
{
    int g = blockIdx.x * blockDim.x + threadIdx.x;
    if (g > G) return;
    int lo = 0, hi = N;
    while (lo < hi) {
        int mid = (lo + hi) >> 1;
        if (batch[mid] < g) lo = mid + 1; else hi = mid;
    }
    off_g[g] = lo;
}

// ---------------- pool + MLP: one block per graph --------------------------
__global__ __launch_bounds__(128) void pool_mlp(
    const float* __restrict__ nodex, const int* __restrict__ off_g,
    const float* __restrict__ l2w, const float* __restrict__ l2b,
    const float* __restrict__ l3w, const float* __restrict__ l3b,
    float* __restrict__ pred, int G)
{
    int g = blockIdx.x;
    int t = threadIdx.x;
    int s = off_g[g], e = off_g[g + 1];
    float acc = 0.f;
    for (int n = s; n < e; ++n) acc += nodex[(size_t)n * 128 + t];
    float cnt = (float)(e - s);
    __shared__ float gx[128];
    __shared__ float hid[64];
    gx[t] = acc / fmaxf(cnt, 1.f);
    __syncthreads();
    if (t < 64) {
        float a = l2b[t];
        const float* w = l2w + t * 128;
        #pragma unroll 8
        for (int k = 0; k < 128; ++k) a += w[k] * gx[k];
        hid[t] = fmaxf(a, 0.f);
    }
    __syncthreads();
    if (t < 5) {
        float a = l3b[t];
        const float* w = l3w + t * 64;
        for (int k = 0; k < 64; ++k) a += w[k] * hid[k];
        pred[g * 5 + t] = a;
    }
}

// ---------------------------------------------------------------------------
extern "C" void kernel_launch(void* const* d_in, const int* in_sizes, int n_in,
                              void* d_out, int out_size, void* d_ws, size_t ws_size,
                              hipStream_t stream)
{
    const float* x      = (const float*)d_in[0];
    const int*   eidx   = (const int*)d_in[1];
    const float* eattr  = (const float*)d_in[2];
    const int*   batch  = (const int*)d_in[3];
    const float* c1w    = (const float*)d_in[5];
    const float* c1b    = (const float*)d_in[6];
    const float* c2w    = (const float*)d_in[7];
    const float* c2b    = (const float*)d_in[8];
    const float* l1w    = (const float*)d_in[9];
    const float* l1b    = (const float*)d_in[10];
    const float* gamma  = (const float*)d_in[11];
    const float* beta   = (const float*)d_in[12];
    const float* l2w    = (const float*)d_in[13];
    const float* l2b    = (const float*)d_in[14];
    const float* l3w    = (const float*)d_in[15];
    const float* l3b    = (const float*)d_in[16];

    const int N = in_sizes[3];
    const int E = in_sizes[2];
    const int G = (out_size - N * 128) / 5;

    const int* erow = eidx;       // edge_index[0]
    const int* ecol = eidx + E;   // edge_index[1]

    // ---- workspace carve-up ----
    char* p = (char*)d_ws;
    auto alloc = [&](size_t bytes) -> void* {
        void* r = (void*)p;
        p += (bytes + 255) & ~(size_t)255;
        return r;
    };
    float*   h2     = (float*)alloc((size_t)N * 245 * sizeof(float));
    uint32*  h0     = (uint32*)alloc((size_t)N * 64 * sizeof(uint32)); // bf16x2
    uint32*  hA     = (uint32*)alloc((size_t)N * 64 * sizeof(uint32));
    uint32*  hB     = (uint32*)alloc((size_t)N * 64 * sizeof(uint32));
    float*   deg    = (float*)alloc((size_t)N * sizeof(float));
    float*   dinv   = (float*)alloc((size_t)N * sizeof(float));
    float*   bnsum  = (float*)alloc(256 * sizeof(float));
    float*   bnssq  = bnsum + 128;
    float2*  edges  = (float2*)alloc((size_t)E * sizeof(float2));
    float*   wT     = (float*)alloc((size_t)245 * 128 * sizeof(float));
    int*     cnt    = (int*)alloc((size_t)N * sizeof(int));
    int*     off    = (int*)alloc((size_t)(N + 1) * sizeof(int));
    int*     cursor = (int*)alloc((size_t)N * sizeof(int));
    int*     off_g  = (int*)alloc((size_t)(G + 1) * sizeof(int));
    const int SB = (N + 1023) / 1024;
    int*     bsum   = (int*)alloc((size_t)SB * sizeof(int));
    int*     boff   = (int*)alloc((size_t)SB * sizeof(int));

    float* pred  = (float*)d_out;
    float* nodex = (float*)d_out + (size_t)G * 5;

    // ---- zero-init accumulators (ws is poisoned before every call) ----
    hipMemsetAsync(deg, 0, (size_t)N * sizeof(float), stream);
    hipMemsetAsync(cnt, 0, (size_t)N * sizeof(int), stream);
    hipMemsetAsync(bnsum, 0, 256 * sizeof(float), stream);

    // ---- CNN encoder ----
    conv_fused<<<N, 320, 0, stream>>>(x, c1w, c1b, c2w, c2b, h2, N);
    transpose_w<<<(128 * 245 + 255) / 256, 256, 0, stream>>>(l1w, wT);
    l1_kernel<<<(N + 63) / 64, 256, 0, stream>>>(h2, wT, l1b, (ushort16*)h0, N);

    // ---- edge normalization + CSR build ----
    int egrid = (E + 255) / 256;
    deg_cnt_kernel<<<egrid, 256, 0, stream>>>(ecol, eattr, deg, cnt, E);
    dinv_kernel<<<(N + 255) / 256, 256, 0, stream>>>(deg, dinv, N);
    scan_block_sums<<<SB, 256, 0, stream>>>(cnt, bsum, N);
    scan_block_offsets<<<1, 256, 0, stream>>>(bsum, boff, SB, &off[N], E);
    scan_write<<<SB, 256, 0, stream>>>(cnt, boff, off, cursor, N);
    scatter_edges<<<egrid, 256, 0, stream>>>(erow, ecol, eattr, dinv, cursor,
                                             edges, E);

    // ---- APPNP hops (bf16 h) ----
    dim3 hopblk(64, 4);
    int hopgrid = (N + 3) / 4;
    appnp_hop<<<hopgrid, hopblk, 0, stream>>>(h0, h0, hA, off, edges, N);
    appnp_hop<<<hopgrid, hopblk, 0, stream>>>(hA, h0, hB, off, edges, N);

    // ---- BatchNorm ----
    bn_reduce<<<256, 256, 0, stream>>>(hB, bnsum, bnssq, N);
    bn_apply<<<(N * 64 + 255) / 256, 256, 0, stream>>>(hB, bnsum, bnssq, gamma,
                                                       beta, (float2*)nodex, N);

    // ---- pool + MLP ----
    graph_bounds<<<(G + 1 + 255) / 256, 256, 0, stream>>>(batch, off_g, N, G);
    pool_mlp<<<G, 128, 0, stream>>>(nodex, off_g, l2w, l2b, l3w, l3b, pred, G);
}